// Round 13
// baseline (247.345 us; speedup 1.0000x reference)
//
#include <hip/hip_runtime.h>
#include <hip/hip_bf16.h>
#include <cstdint>

typedef __bf16 bf16_t;
typedef bf16_t bf16x8 __attribute__((ext_vector_type(8)));
typedef float f32x4 __attribute__((ext_vector_type(4)));
typedef float f32x16 __attribute__((ext_vector_type(16)));

// B=4, S=4096, DIM=1024, H=16, HD=64, M=64
// QKV layout: [16384][3072] bf16, cols 0-1023 = Q', 1024-2047 = K', 2048-3071 = V

__device__ __forceinline__ void gload_lds16(const bf16_t* g, bf16_t* l) {
  __builtin_amdgcn_global_load_lds(
      (const __attribute__((address_space(1))) uint32_t*)g,
      (__attribute__((address_space(3))) uint32_t*)l, 16, 0, 0);
}

// ---------------- merged prep: cast x, cast Wv, copy bv, fold P into Wq/Wk ------
// block ranges: [0,8192) x-cast | [8192,8704) Wv-cast | 8704 bv | [8705,8961) wqk
__global__ __launch_bounds__(256) void prep_all(
    const float* __restrict__ x, const float* __restrict__ Wv,
    const float* __restrict__ bv,
    const float* __restrict__ Wq, const float* __restrict__ bq,
    const float* __restrict__ Wk, const float* __restrict__ bk,
    const float* __restrict__ P,
    bf16_t* __restrict__ xb, bf16_t* __restrict__ Wcat, float* __restrict__ bcat)
{
  __shared__ float Pl[64 * 64];
  __shared__ float Wlt[128 * 68];
  int b = blockIdx.x, t = threadIdx.x;
  if (b < 8192) {
    long i = (long)b * 256 + t;
    const f32x4* p = (const f32x4*)(x + i * 8);
    f32x4 a = p[0], c = p[1];
    bf16x8 o;
#pragma unroll
    for (int j = 0; j < 4; ++j) { o[j] = (bf16_t)a[j]; o[j + 4] = (bf16_t)c[j]; }
    *(bf16x8*)(xb + i * 8) = o;
  } else if (b < 8704) {
    long i = (long)(b - 8192) * 256 + t;
    const f32x4* p = (const f32x4*)(Wv + i * 8);
    f32x4 a = p[0], c = p[1];
    bf16x8 o;
#pragma unroll
    for (int j = 0; j < 4; ++j) { o[j] = (bf16_t)a[j]; o[j + 4] = (bf16_t)c[j]; }
    *(bf16x8*)(Wcat + (size_t)2048 * 1024 + i * 8) = o;
  } else if (b == 8704) {
    *(f32x4*)&bcat[2048 + t * 4] = *(const f32x4*)&bv[t * 4];
  } else {
    // fold: WQP[h*64+m][k] = sum_d P[h][m][d]*W[h*64+d][k]
    int bid = b - 8705;
    int qk = bid >> 7, h = (bid >> 3) & 15, kt = bid & 7;
    const float* W = qk ? Wk : Wq;
    const float* bias = qk ? bk : bq;
    int k0 = kt * 128;
    for (int i = t * 4; i < 4096; i += 1024)
      *(f32x4*)&Pl[i] = *(const f32x4*)&P[h * 4096 + i];
    for (int fi = t; fi < 2048; fi += 256) {
      int row = fi >> 5;
      int c4 = fi & 31;
      f32x4 w = *(const f32x4*)&W[(long)(h * 64 + row) * 1024 + k0 + c4 * 4];
#pragma unroll
      for (int j = 0; j < 4; ++j) Wlt[(c4 * 4 + j) * 68 + row] = w[j];
    }
    __syncthreads();
    int kloc = t >> 1;
    int mh = (t & 1) * 32;
    for (int m = mh; m < mh + 32; ++m) {
      f32x4 s = {0.f, 0.f, 0.f, 0.f};
#pragma unroll
      for (int dd = 0; dd < 16; ++dd)
        s += (*(const f32x4*)&Pl[m * 64 + dd * 4]) * (*(const f32x4*)&Wlt[kloc * 68 + dd * 4]);
      float a = s[0] + s[1] + s[2] + s[3];
      Wcat[(long)(qk * 1024 + h * 64 + m) * 1024 + k0 + kloc] = (bf16_t)a;
    }
    if (kt == 0 && t < 64) {
      float a = 0.f;
      for (int d = 0; d < 64; ++d) a += Pl[t * 64 + d] * bias[h * 64 + d];
      bcat[qk * 1024 + h * 64 + t] = a;
    }
  }
}

// ---------------- 256x256 GEMM: r1 loop, 32x32x16 MFMA, XOR-swizzled LDS ---------
// C[M,N] = A[M,K] @ B[N,K]^T + bias.  EPI=1: bf16 out, relu*0.125 for gcol<2048.
// EPI=2: fp32 out.
// Per wave 128x64 = 4(mi,32row) x 2(ni,32col) tiles of f32x16.
// A/B frag: row = l&31, k = (l>>5)*8+elem -> LDS chunk kq = 2*kstep + (l>>5),
// addr = row*64 + (kq ^ (row&7))*8. Note (r9/r10 findings): the residual 9.4M
// bank-conflict count is the 32x32-fragment/row-stride-128B geometry floor
// (~4cyc/b128); removing it requires scattering the staging source (-20%, r10).
template <int EPI>
__global__ __launch_bounds__(512, 2) void gemm256(
    const bf16_t* __restrict__ A, int lda,
    const bf16_t* __restrict__ B0, int ldb,
    const float* __restrict__ bias,
    void* __restrict__ Cv, int ldc,
    int K, int ncols, int cpx,
    int rows_per_batch, long bstride)
{
  __shared__ bf16_t sA[2][16384];
  __shared__ bf16_t sB[2][16384];

  const int lin = blockIdx.x;
  const int wgid = (lin & 7) * cpx + (lin >> 3);
  const int row0 = (wgid / ncols) * 256;
  const int col0 = (wgid % ncols) * 256;

  const int tid = threadIdx.x;
  const int w = tid >> 6, l = tid & 63;
  const int wr = w >> 2, wc = w & 3;          // wave grid 2(M) x 4(N)
  const int l31 = l & 31, kh = l >> 5, x7 = l & 7;

  const bf16_t* Bm = B0 + (long)(row0 / rows_per_batch) * bstride;

  long a_off[4], b_off[4];
#pragma unroll
  for (int i = 0; i < 4; ++i) {
    int c = i * 512 + tid;
    int r = c >> 3;
    int kqs = (c & 7) ^ (r & 7);
    a_off[i] = (long)(row0 + r) * lda + kqs * 8;
    b_off[i] = (long)(col0 + r) * ldb + kqs * 8;
  }
  const int ldst = tid * 8;

  // ds_read bases; chunk offset per kstep s: ((2s + kh) ^ x7) * 8
  const int abase = (wr * 128 + l31) * 64;
  const int bbase = (wc * 64 + l31) * 64;
  const int e0 = ((0 + kh) ^ x7) * 8;   // kstep 0
  const int e1 = ((2 + kh) ^ x7) * 8;   // kstep 1
  const int e2 = ((4 + kh) ^ x7) * 8;   // kstep 2
  const int e3 = ((6 + kh) ^ x7) * 8;   // kstep 3

  f32x16 acc[4][2] = {};
  const int NT = K >> 6;

#pragma unroll
  for (int i = 0; i < 4; ++i) {
    gload_lds16(A + a_off[i], &sA[0][i * 4096 + ldst]);
    gload_lds16(Bm + b_off[i], &sB[0][i * 4096 + ldst]);
  }
  __syncthreads();

#define TILE_BODY(PC, PN, T)                                                            \
  {                                                                                     \
    bf16x8 afr[4][2], bfr[2][2];                                                        \
    _Pragma("unroll") for (int mi = 0; mi < 4; ++mi) {                                  \
      afr[mi][0] = *(const bf16x8*)&sA[PC][abase + mi * 2048 + e0];                     \
      afr[mi][1] = *(const bf16x8*)&sA[PC][abase + mi * 2048 + e1];                     \
    }                                                                                   \
    _Pragma("unroll") for (int ni = 0; ni < 2; ++ni) {                                  \
      bfr[ni][0] = *(const bf16x8*)&sB[PC][bbase + ni * 2048 + e0];                     \
      bfr[ni][1] = *(const bf16x8*)&sB[PC][bbase + ni * 2048 + e1];                     \
    }                                                                                   \
    if ((T) + 1 < NT) {                                                                 \
      long ks = (long)((T) + 1) * 64;                                                   \
      _Pragma("unroll") for (int i = 0; i < 4; ++i) {                                   \
        gload_lds16(A + a_off[i] + ks, &sA[PN][i * 4096 + ldst]);                       \
        gload_lds16(Bm + b_off[i] + ks, &sB[PN][i * 4096 + ldst]);                      \
      }                                                                                 \
    }                                                                                   \
    __builtin_amdgcn_s_setprio(1);                                                      \
    _Pragma("unroll") for (int mi = 0; mi < 4; ++mi)                                    \
      _Pragma("unroll") for (int ni = 0; ni < 2; ++ni) {                                \
        acc[mi][ni] = __builtin_amdgcn_mfma_f32_32x32x16_bf16(afr[mi][0], bfr[ni][0], acc[mi][ni], 0, 0, 0); \
        acc[mi][ni] = __builtin_amdgcn_mfma_f32_32x32x16_bf16(afr[mi][1], bfr[ni][1], acc[mi][ni], 0, 0, 0); \
      }                                                                                 \
    __builtin_amdgcn_s_setprio(0);                                                      \
    _Pragma("unroll") for (int mi = 0; mi < 4; ++mi) {                                  \
      afr[mi][0] = *(const bf16x8*)&sA[PC][abase + mi * 2048 + e2];                     \
      afr[mi][1] = *(const bf16x8*)&sA[PC][abase + mi * 2048 + e3];                     \
    }                                                                                   \
    _Pragma("unroll") for (int ni = 0; ni < 2; ++ni) {                                  \
      bfr[ni][0] = *(const bf16x8*)&sB[PC][bbase + ni * 2048 + e2];                     \
      bfr[ni][1] = *(const bf16x8*)&sB[PC][bbase + ni * 2048 + e3];                     \
    }                                                                                   \
    __builtin_amdgcn_s_setprio(1);                                                      \
    _Pragma("unroll") for (int mi = 0; mi < 4; ++mi)                                    \
      _Pragma("unroll") for (int ni = 0; ni < 2; ++ni) {                                \
        acc[mi][ni] = __builtin_amdgcn_mfma_f32_32x32x16_bf16(afr[mi][0], bfr[ni][0], acc[mi][ni], 0, 0, 0); \
        acc[mi][ni] = __builtin_amdgcn_mfma_f32_32x32x16_bf16(afr[mi][1], bfr[ni][1], acc[mi][ni], 0, 0, 0); \
      }                                                                                 \
    __builtin_amdgcn_s_setprio(0);                                                      \
    __syncthreads();                                                                    \
  }

  for (int t = 0; t < NT; t += 2) {
    TILE_BODY(0, 1, t);
    TILE_BODY(1, 0, t + 1);
  }
#undef TILE_BODY

  // epilogue: 32x32 C/D layout col=lane&31, row=(reg&3)+8*(reg>>2)+4*(lane>>5)
#pragma unroll
  for (int ni = 0; ni < 2; ++ni) {
    const int gcol = col0 + wc * 64 + ni * 32 + l31;
    const float bz = bias[gcol];
    const bool doRelu = (EPI == 1) && (gcol < 2048);
#pragma unroll
    for (int mi = 0; mi < 4; ++mi) {
      const int rbase = row0 + wr * 128 + mi * 32 + 4 * kh;
#pragma unroll
      for (int reg = 0; reg < 16; ++reg) {
        const int grow = rbase + (reg & 3) + 8 * (reg >> 2);
        float v = acc[mi][ni][reg] + bz;
        if constexpr (EPI == 1) { if (doRelu) v = fmaxf(v, 0.f) * 0.125f; }
        if constexpr (EPI == 2)
          ((float*)Cv)[(long)grow * ldc + gcol] = v;
        else
          ((bf16_t*)Cv)[(long)grow * ldc + gcol] = (bf16_t)v;
      }
    }
  }
}

// ---------------- 128x128 GEMM: same loop, 32x32x16, XOR LDS, 2 blocks/CU --------
__global__ __launch_bounds__(512, 4) void gemm128(
    const bf16_t* __restrict__ A, int lda,
    const bf16_t* __restrict__ B0, int ldb,
    const float* __restrict__ bias,
    float* __restrict__ C, int ldc,
    int K, int ncols, int cpx,
    int rows_per_batch, long bstride)
{
  __shared__ bf16_t sA[2][8192];
  __shared__ bf16_t sB[2][8192];

  const int lin = blockIdx.x;
  const int wgid = (lin & 7) * cpx + (lin >> 3);
  const int row0 = (wgid / ncols) * 128;
  const int col0 = (wgid % ncols) * 128;

  const int tid = threadIdx.x;
  const int w = tid >> 6, l = tid & 63;
  const int wr = w >> 2, wc = w & 3;
  const int l31 = l & 31, kh = l >> 5, x7 = l & 7;

  const bf16_t* Bm = B0 + (long)(row0 / rows_per_batch) * bstride;

  long a_off[2], b_off[2];
#pragma unroll
  for (int i = 0; i < 2; ++i) {
    int c = i * 512 + tid;
    int r = c >> 3;
    int kqs = (c & 7) ^ (r & 7);
    a_off[i] = (long)(row0 + r) * lda + kqs * 8;
    b_off[i] = (long)(col0 + r) * ldb + kqs * 8;
  }
  const int ldst = tid * 8;

  const int abase = (wr * 64 + l31) * 64;
  const int bbase = (wc * 32 + l31) * 64;
  const int e0 = ((0 + kh) ^ x7) * 8;
  const int e1 = ((2 + kh) ^ x7) * 8;
  const int e2 = ((4 + kh) ^ x7) * 8;
  const int e3 = ((6 + kh) ^ x7) * 8;

  f32x16 acc[2] = {};
  const int NT = K >> 6;

#pragma unroll
  for (int i = 0; i < 2; ++i) {
    gload_lds16(A + a_off[i], &sA[0][i * 4096 + ldst]);
    gload_lds16(Bm + b_off[i], &sB[0][i * 4096 + ldst]);
  }
  __syncthreads();

#define TILE128(PC, PN, T)                                                              \
  {                                                                                     \
    bf16x8 afr[2][2], bfr[2];                                                           \
    _Pragma("unroll") for (int mi = 0; mi < 2; ++mi) {                                  \
      afr[mi][0] = *(const bf16x8*)&sA[PC][abase + mi * 2048 + e0];                     \
      afr[mi][1] = *(const bf16x8*)&sA[PC][abase + mi * 2048 + e1];                     \
    }                                                                                   \
    bfr[0] = *(const bf16x8*)&sB[PC][bbase + e0];                                       \
    bfr[1] = *(const bf16x8*)&sB[PC][bbase + e1];                                       \
    if ((T) + 1 < NT) {                                                                 \
      long ks = (long)((T) + 1) * 64;                                                   \
      _Pragma("unroll") for (int i = 0; i < 2; ++i) {                                   \
        gload_lds16(A + a_off[i] + ks, &sA[PN][i * 4096 + ldst]);                       \
        gload_lds16(Bm + b_off[i] + ks, &sB[PN][i * 4096 + ldst]);                      \
      }                                                                                 \
    }                                                                                   \
    __builtin_amdgcn_s_setprio(1);                                                      \
    _Pragma("unroll") for (int mi = 0; mi < 2; ++mi) {                                  \
      acc[mi] = __builtin_amdgcn_mfma_f32_32x32x16_bf16(afr[mi][0], bfr[0], acc[mi], 0, 0, 0); \
      acc[mi] = __builtin_amdgcn_mfma_f32_32x32x16_bf16(afr[mi][1], bfr[1], acc[mi], 0, 0, 0); \
    }                                                                                   \
    __builtin_amdgcn_s_setprio(0);                                                      \
    _Pragma("unroll") for (int mi = 0; mi < 2; ++mi) {                                  \
      afr[mi][0] = *(const bf16x8*)&sA[PC][abase + mi * 2048 + e2];                     \
      afr[mi][1] = *(const bf16x8*)&sA[PC][abase + mi * 2048 + e3];                     \
    }                                                                                   \
    bfr[0] = *(const bf16x8*)&sB[PC][bbase + e2];                                       \
    bfr[1] = *(const bf16x8*)&sB[PC][bbase + e3];                                       \
    __builtin_amdgcn_s_setprio(1);                                                      \
    _Pragma("unroll") for (int mi = 0; mi < 2; ++mi) {                                  \
      acc[mi] = __builtin_amdgcn_mfma_f32_32x32x16_bf16(afr[mi][0], bfr[0], acc[mi], 0, 0, 0); \
      acc[mi] = __builtin_amdgcn_mfma_f32_32x32x16_bf16(afr[mi][1], bfr[1], acc[mi], 0, 0, 0); \
    }                                                                                   \
    __builtin_amdgcn_s_setprio(0);                                                      \
    __syncthreads();                                                                    \
  }

  for (int t = 0; t < NT; t += 2) {
    TILE128(0, 1, t);
    TILE128(1, 0, t + 1);
  }
#undef TILE128

  const int gcol = col0 + wc * 32 + l31;
  const float bz = bias[gcol];
#pragma unroll
  for (int mi = 0; mi < 2; ++mi) {
    const int rbase = row0 + wr * 64 + mi * 32 + 4 * kh;
#pragma unroll
    for (int reg = 0; reg < 16; ++reg) {
      const int grow = rbase + (reg & 3) + 8 * (reg >> 2);
      C[(long)grow * ldc + gcol] = acc[mi][reg] + bz;
    }
  }
}

// ---------------- kv partial: kv[b,h,m,d] = sum_s K'[b,s,h,m]*V[b,s,h,d] ----------------
__global__ __launch_bounds__(256) void kv_partial(
    const bf16_t* __restrict__ QKV, float* __restrict__ kvpart)
{
  int bh = blockIdx.x;
  int split = blockIdx.y;
  int b = bh >> 4, h = bh & 15;
  __shared__ alignas(16) bf16_t Kt[64 * 32];
  __shared__ alignas(16) bf16_t Vt[64 * 32];
  int t = threadIdx.x;
  int wv = t >> 6, lane = t & 63, lhi = lane >> 4, llo = lane & 15;
  int r = t >> 3;
  int c = (t & 7) * 8;
  f32x4 acc[4] = {};
  long rowbase = ((long)b * 4096 + split * 512) * 3072 + h * 64 + c;
  for (int sc = 0; sc < 16; ++sc) {
    long off = rowbase + (long)(sc * 32 + r) * 3072;
    bf16x8 kk = *(const bf16x8*)(QKV + off + 1024);
    bf16x8 vvv = *(const bf16x8*)(QKV + off + 2048);
#pragma unroll
    for (int j = 0; j < 8; ++j) {
      Kt[(c + j) * 32 + r] = kk[j];
      Vt[(c + j) * 32 + r] = vvv[j];
    }
    __syncthreads();
    bf16x8 a = *(const bf16x8*)&Kt[(wv * 16 + llo) * 32 + lhi * 8];
#pragma unroll
    for (int ni = 0; ni < 4; ++ni) {
      bf16x8 bb = *(const bf16x8*)&Vt[(ni * 16 + llo) * 32 + lhi * 8];
      acc[ni] = __builtin_amdgcn_mfma_f32_16x16x32_bf16(a, bb, acc[ni], 0, 0, 0);
    }
    __syncthreads();
  }
#pragma unroll
  for (int ni = 0; ni < 4; ++ni)
#pragma unroll
    for (int j = 0; j < 4; ++j) {
      int m = wv * 16 + lhi * 4 + j;
      int d = ni * 16 + llo;
      kvpart[((long)split * 64 + bh) * 4096 + m * 64 + d] = acc[ni][j];
    }
}

// ---------------- WcombT[b][n][h*64+m] = sum_d kv[b,h,m,d] * Wo[n][h*64+d] -------
// kv materialized in LDS by summing the 8 kvpart splits (kv_reduce fused).
__global__ __launch_bounds__(256) void wcombt_kernel(
    const float* __restrict__ kvpart, const float* __restrict__ Wo,
    bf16_t* __restrict__ WcT)
{
  int nt = blockIdx.x, h = blockIdx.y, b = blockIdx.z;
  __shared__ float kvs[4096];
  int t = threadIdx.x;
  const long base = ((long)b * 16 + h) * 4096;
  for (int i = t * 4; i < 4096; i += 1024) {
    f32x4 s = {0.f, 0.f, 0.f, 0.f};
#pragma unroll
    for (int sp = 0; sp < 8; ++sp)
      s += *(const f32x4*)&kvpart[(long)sp * 262144 + base + i];
    *(f32x4*)&kvs[i] = s;
  }
  __syncthreads();
  int n = nt * 128 + (t >> 1);
  int mh = (t & 1) * 32;
  f32x4 wo[16];
#pragma unroll
  for (int dd = 0; dd < 16; ++dd) wo[dd] = *(const f32x4*)&Wo[(long)n * 1024 + h * 64 + dd * 4];
  for (int m = mh; m < mh + 32; ++m) {
    f32x4 s = {0.f, 0.f, 0.f, 0.f};
#pragma unroll
    for (int dd = 0; dd < 16; ++dd)
      s += (*(const f32x4*)&kvs[m * 64 + dd * 4]) * wo[dd];
    WcT[((long)b * 1024 + n) * 1024 + h * 64 + m] = (bf16_t)(s[0] + s[1] + s[2] + s[3]);
  }
}

// ---------------- launch ----------------
extern "C" void kernel_launch(void* const* d_in, const int* in_sizes, int n_in,
                              void* d_out, int out_size, void* d_ws, size_t ws_size,
                              hipStream_t stream) {
  (void)in_sizes; (void)n_in; (void)out_size; (void)ws_size;
  const float* x  = (const float*)d_in[0];
  const float* Wq = (const float*)d_in[1];
  const float* bq = (const float*)d_in[2];
  const float* Wk = (const float*)d_in[3];
  const float* bk = (const float*)d_in[4];
  const float* Wv = (const float*)d_in[5];
  const float* bv = (const float*)d_in[6];
  const float* Wo = (const float*)d_in[7];
  const float* bo = (const float*)d_in[8];
  const float* P  = (const float*)d_in[9];
  float* out = (float*)d_out;

  char* ws = (char*)d_ws;
  bf16_t* xb     = (bf16_t*)(ws + 0);            // 32 MB
  bf16_t* QKV    = (bf16_t*)(ws + 33554432);     // 96 MB
  bf16_t* Wcat   = (bf16_t*)(ws + 134217728);    // 6 MB
  float*  bcat   = (float*) (ws + 140509184);    // 12 KB
  float*  kvpart = (float*) (ws + 140521472);    // 8 MB
  bf16_t* WcT    = (bf16_t*)(ws + 149958656);    // 8 MB

  // 1. merged prep: casts + bv copy + P-fold in ONE launch (disjoint outputs)
  prep_all<<<8961, 256, 0, stream>>>(x, Wv, bv, Wq, bq, Wk, bk, P, xb, Wcat, bcat);

  // 2. fused Q'/K'/V GEMM: [16384,1024] x [3072,1024]^T -> [16384,3072]
  //    grid 64 x 12 = 768 blocks, cpx = 96
  gemm256<1><<<768, 512, 0, stream>>>(
      xb, 1024, Wcat, 1024, bcat, QKV, 3072, 1024, 12, 96, 1 << 30, 0);

  // 3. kv = K'^T @ V per (b,h), 8-way split over s (reduce fused into step 4)
  kv_partial<<<dim3(64, 8), 256, 0, stream>>>(QKV, kvpart);

  // 4. fold kv into Wo: WcombT per batch (sums the 8 splits in-kernel)
  wcombt_kernel<<<dim3(8, 16, 4), 256, 0, stream>>>(kvpart, Wo, WcT);

  // 5. out = Q' @ WcombT[b]^T + bo  (fp32 out) — 128^2 tile, 2 blocks/CU
  //    grid 128 x 8 = 1024 blocks, cpx = 128
  gemm128<<<1024, 512, 0, stream>>>(
      QKV, 3072, WcT, 1024, bo, out, 1024, 1024, 8, 128, 4096, (long)1024 * 1024);
}

// Round 14
// 236.729 us; speedup vs baseline: 1.0448x; 1.0448x over previous
//
#include <hip/hip_runtime.h>
#include <hip/hip_bf16.h>
#include <cstdint>

typedef __bf16 bf16_t;
typedef bf16_t bf16x8 __attribute__((ext_vector_type(8)));
typedef float f32x4 __attribute__((ext_vector_type(4)));
typedef float f32x16 __attribute__((ext_vector_type(16)));

// B=4, S=4096, DIM=1024, H=16, HD=64, M=64
// QKV layout: [16384][3072] bf16, cols 0-1023 = Q', 1024-2047 = K', 2048-3071 = V

__device__ __forceinline__ void gload_lds16(const bf16_t* g, bf16_t* l) {
  __builtin_amdgcn_global_load_lds(
      (const __attribute__((address_space(1))) uint32_t*)g,
      (__attribute__((address_space(3))) uint32_t*)l, 16, 0, 0);
}

// ---------------- merged prep: cast x, cast Wv, copy bv (one launch, NO LDS) ----
__global__ void prep_misc(const float* __restrict__ x, const float* __restrict__ Wv,
                          const float* __restrict__ bv,
                          bf16_t* __restrict__ xb, bf16_t* __restrict__ WvO,
                          float* __restrict__ bcat) {
  int b = blockIdx.x, t = threadIdx.x;
  if (b < 8192) {
    long i = (long)b * 256 + t;
    const f32x4* p = (const f32x4*)(x + i * 8);
    f32x4 a = p[0], c = p[1];
    bf16x8 o;
#pragma unroll
    for (int j = 0; j < 4; ++j) { o[j] = (bf16_t)a[j]; o[j + 4] = (bf16_t)c[j]; }
    *(bf16x8*)(xb + i * 8) = o;
  } else if (b < 8704) {
    long i = (long)(b - 8192) * 256 + t;
    const f32x4* p = (const f32x4*)(Wv + i * 8);
    f32x4 a = p[0], c = p[1];
    bf16x8 o;
#pragma unroll
    for (int j = 0; j < 4; ++j) { o[j] = (bf16_t)a[j]; o[j + 4] = (bf16_t)c[j]; }
    *(bf16x8*)(WvO + i * 8) = o;
  } else {
    *(f32x4*)&bcat[2048 + t * 4] = *(const f32x4*)&bv[t * 4];
  }
}

// ---------------- fold P into Wq/Wk:  WQP[h*64+m][k] = sum_d P[h][m][d]*W[h*64+d][k] ----------------
__global__ __launch_bounds__(256) void prep_wqk(
    const float* __restrict__ Wq, const float* __restrict__ bq,
    const float* __restrict__ Wk, const float* __restrict__ bk,
    const float* __restrict__ P,
    bf16_t* __restrict__ Wcat, float* __restrict__ bcat)
{
  int bid = blockIdx.x;
  int qk = bid >> 7, h = (bid >> 3) & 15, kt = bid & 7;
  const float* W = qk ? Wk : Wq;
  const float* bias = qk ? bk : bq;
  __shared__ float Pl[64 * 64];
  __shared__ float Wlt[128 * 68];
  int t = threadIdx.x;
  int k0 = kt * 128;
  for (int i = t * 4; i < 4096; i += 1024)
    *(f32x4*)&Pl[i] = *(const f32x4*)&P[h * 4096 + i];
  for (int fi = t; fi < 2048; fi += 256) {
    int row = fi >> 5;
    int c4 = fi & 31;
    f32x4 w = *(const f32x4*)&W[(long)(h * 64 + row) * 1024 + k0 + c4 * 4];
#pragma unroll
    for (int j = 0; j < 4; ++j) Wlt[(c4 * 4 + j) * 68 + row] = w[j];
  }
  __syncthreads();
  int kloc = t >> 1;
  int mh = (t & 1) * 32;
  for (int m = mh; m < mh + 32; ++m) {
    f32x4 s = {0.f, 0.f, 0.f, 0.f};
#pragma unroll
    for (int dd = 0; dd < 16; ++dd)
      s += (*(const f32x4*)&Pl[m * 64 + dd * 4]) * (*(const f32x4*)&Wlt[kloc * 68 + dd * 4]);
    float a = s[0] + s[1] + s[2] + s[3];
    Wcat[(long)(qk * 1024 + h * 64 + m) * 1024 + k0 + kloc] = (bf16_t)a;
  }
  if (kt == 0 && t < 64) {
    float a = 0.f;
    for (int d = 0; d < 64; ++d) a += Pl[t * 64 + d] * bias[h * 64 + d];
    bcat[qk * 1024 + h * 64 + t] = a;
  }
}

// ---------------- 256x256 GEMM: r1 loop, 32x32x16 MFMA, XOR-swizzled LDS ---------
// C[M,N] = A[M,K] @ B[N,K]^T + bias.  EPI=1: bf16 out, relu*0.125 for gcol<2048.
// EPI=2: fp32 out.
// Per wave 128x64 = 4(mi,32row) x 2(ni,32col) tiles of f32x16.
// A/B frag: row = l&31, k = (l>>5)*8+elem -> LDS chunk kq = 2*kstep + (l>>5),
// addr = row*64 + (kq ^ (row&7))*8. Note (r9/r10 findings): the residual 9.4M
// bank-conflict count is the 32x32-fragment/row-stride-128B geometry floor
// (~4cyc/b128); removing it requires scattering the staging source (-20%, r10).
template <int EPI>
__global__ __launch_bounds__(512, 2) void gemm256(
    const bf16_t* __restrict__ A, int lda,
    const bf16_t* __restrict__ B0, int ldb,
    const float* __restrict__ bias,
    void* __restrict__ Cv, int ldc,
    int K, int ncols, int cpx,
    int rows_per_batch, long bstride)
{
  __shared__ bf16_t sA[2][16384];
  __shared__ bf16_t sB[2][16384];

  const int lin = blockIdx.x;
  const int wgid = (lin & 7) * cpx + (lin >> 3);
  const int row0 = (wgid / ncols) * 256;
  const int col0 = (wgid % ncols) * 256;

  const int tid = threadIdx.x;
  const int w = tid >> 6, l = tid & 63;
  const int wr = w >> 2, wc = w & 3;          // wave grid 2(M) x 4(N)
  const int l31 = l & 31, kh = l >> 5, x7 = l & 7;

  const bf16_t* Bm = B0 + (long)(row0 / rows_per_batch) * bstride;

  long a_off[4], b_off[4];
#pragma unroll
  for (int i = 0; i < 4; ++i) {
    int c = i * 512 + tid;
    int r = c >> 3;
    int kqs = (c & 7) ^ (r & 7);
    a_off[i] = (long)(row0 + r) * lda + kqs * 8;
    b_off[i] = (long)(col0 + r) * ldb + kqs * 8;
  }
  const int ldst = tid * 8;

  // ds_read bases; chunk offset per kstep s: ((2s + kh) ^ x7) * 8
  const int abase = (wr * 128 + l31) * 64;
  const int bbase = (wc * 64 + l31) * 64;
  const int e0 = ((0 + kh) ^ x7) * 8;   // kstep 0
  const int e1 = ((2 + kh) ^ x7) * 8;   // kstep 1
  const int e2 = ((4 + kh) ^ x7) * 8;   // kstep 2
  const int e3 = ((6 + kh) ^ x7) * 8;   // kstep 3

  f32x16 acc[4][2] = {};
  const int NT = K >> 6;

#pragma unroll
  for (int i = 0; i < 4; ++i) {
    gload_lds16(A + a_off[i], &sA[0][i * 4096 + ldst]);
    gload_lds16(Bm + b_off[i], &sB[0][i * 4096 + ldst]);
  }
  __syncthreads();

#define TILE_BODY(PC, PN, T)                                                            \
  {                                                                                     \
    bf16x8 afr[4][2], bfr[2][2];                                                        \
    _Pragma("unroll") for (int mi = 0; mi < 4; ++mi) {                                  \
      afr[mi][0] = *(const bf16x8*)&sA[PC][abase + mi * 2048 + e0];                     \
      afr[mi][1] = *(const bf16x8*)&sA[PC][abase + mi * 2048 + e1];                     \
    }                                                                                   \
    _Pragma("unroll") for (int ni = 0; ni < 2; ++ni) {                                  \
      bfr[ni][0] = *(const bf16x8*)&sB[PC][bbase + ni * 2048 + e0];                     \
      bfr[ni][1] = *(const bf16x8*)&sB[PC][bbase + ni * 2048 + e1];                     \
    }                                                                                   \
    if ((T) + 1 < NT) {                                                                 \
      long ks = (long)((T) + 1) * 64;                                                   \
      _Pragma("unroll") for (int i = 0; i < 4; ++i) {                                   \
        gload_lds16(A + a_off[i] + ks, &sA[PN][i * 4096 + ldst]);                       \
        gload_lds16(Bm + b_off[i] + ks, &sB[PN][i * 4096 + ldst]);                      \
      }                                                                                 \
    }                                                                                   \
    __builtin_amdgcn_s_setprio(1);                                                      \
    _Pragma("unroll") for (int mi = 0; mi < 4; ++mi)                                    \
      _Pragma("unroll") for (int ni = 0; ni < 2; ++ni) {                                \
        acc[mi][ni] = __builtin_amdgcn_mfma_f32_32x32x16_bf16(afr[mi][0], bfr[ni][0], acc[mi][ni], 0, 0, 0); \
        acc[mi][ni] = __builtin_amdgcn_mfma_f32_32x32x16_bf16(afr[mi][1], bfr[ni][1], acc[mi][ni], 0, 0, 0); \
      }                                                                                 \
    __builtin_amdgcn_s_setprio(0);                                                      \
    _Pragma("unroll") for (int mi = 0; mi < 4; ++mi) {                                  \
      afr[mi][0] = *(const bf16x8*)&sA[PC][abase + mi * 2048 + e2];                     \
      afr[mi][1] = *(const bf16x8*)&sA[PC][abase + mi * 2048 + e3];                     \
    }                                                                                   \
    _Pragma("unroll") for (int ni = 0; ni < 2; ++ni) {                                  \
      bfr[ni][0] = *(const bf16x8*)&sB[PC][bbase + ni * 2048 + e2];                     \
      bfr[ni][1] = *(const bf16x8*)&sB[PC][bbase + ni * 2048 + e3];                     \
    }                                                                                   \
    __builtin_amdgcn_s_setprio(1);                                                      \
    _Pragma("unroll") for (int mi = 0; mi < 4; ++mi)                                    \
      _Pragma("unroll") for (int ni = 0; ni < 2; ++ni) {                                \
        acc[mi][ni] = __builtin_amdgcn_mfma_f32_32x32x16_bf16(afr[mi][0], bfr[ni][0], acc[mi][ni], 0, 0, 0); \
        acc[mi][ni] = __builtin_amdgcn_mfma_f32_32x32x16_bf16(afr[mi][1], bfr[ni][1], acc[mi][ni], 0, 0, 0); \
      }                                                                                 \
    __builtin_amdgcn_s_setprio(0);                                                      \
    __syncthreads();                                                                    \
  }

  for (int t = 0; t < NT; t += 2) {
    TILE_BODY(0, 1, t);
    TILE_BODY(1, 0, t + 1);
  }
#undef TILE_BODY

  // epilogue: 32x32 C/D layout col=lane&31, row=(reg&3)+8*(reg>>2)+4*(lane>>5)
#pragma unroll
  for (int ni = 0; ni < 2; ++ni) {
    const int gcol = col0 + wc * 64 + ni * 32 + l31;
    const float bz = bias[gcol];
    const bool doRelu = (EPI == 1) && (gcol < 2048);
#pragma unroll
    for (int mi = 0; mi < 4; ++mi) {
      const int rbase = row0 + wr * 128 + mi * 32 + 4 * kh;
#pragma unroll
      for (int reg = 0; reg < 16; ++reg) {
        const int grow = rbase + (reg & 3) + 8 * (reg >> 2);
        float v = acc[mi][ni][reg] + bz;
        if constexpr (EPI == 1) { if (doRelu) v = fmaxf(v, 0.f) * 0.125f; }
        if constexpr (EPI == 2)
          ((float*)Cv)[(long)grow * ldc + gcol] = v;
        else
          ((bf16_t*)Cv)[(long)grow * ldc + gcol] = (bf16_t)v;
      }
    }
  }
}

// ---------------- 128x128 GEMM: same loop, 32x32x16, XOR LDS, 2 blocks/CU --------
__global__ __launch_bounds__(512, 4) void gemm128(
    const bf16_t* __restrict__ A, int lda,
    const bf16_t* __restrict__ B0, int ldb,
    const float* __restrict__ bias,
    float* __restrict__ C, int ldc,
    int K, int ncols, int cpx,
    int rows_per_batch, long bstride)
{
  __shared__ bf16_t sA[2][8192];
  __shared__ bf16_t sB[2][8192];

  const int lin = blockIdx.x;
  const int wgid = (lin & 7) * cpx + (lin >> 3);
  const int row0 = (wgid / ncols) * 128;
  const int col0 = (wgid % ncols) * 128;

  const int tid = threadIdx.x;
  const int w = tid >> 6, l = tid & 63;
  const int wr = w >> 2, wc = w & 3;
  const int l31 = l & 31, kh = l >> 5, x7 = l & 7;

  const bf16_t* Bm = B0 + (long)(row0 / rows_per_batch) * bstride;

  long a_off[2], b_off[2];
#pragma unroll
  for (int i = 0; i < 2; ++i) {
    int c = i * 512 + tid;
    int r = c >> 3;
    int kqs = (c & 7) ^ (r & 7);
    a_off[i] = (long)(row0 + r) * lda + kqs * 8;
    b_off[i] = (long)(col0 + r) * ldb + kqs * 8;
  }
  const int ldst = tid * 8;

  const int abase = (wr * 64 + l31) * 64;
  const int bbase = (wc * 32 + l31) * 64;
  const int e0 = ((0 + kh) ^ x7) * 8;
  const int e1 = ((2 + kh) ^ x7) * 8;
  const int e2 = ((4 + kh) ^ x7) * 8;
  const int e3 = ((6 + kh) ^ x7) * 8;

  f32x16 acc[2] = {};
  const int NT = K >> 6;

#pragma unroll
  for (int i = 0; i < 2; ++i) {
    gload_lds16(A + a_off[i], &sA[0][i * 4096 + ldst]);
    gload_lds16(Bm + b_off[i], &sB[0][i * 4096 + ldst]);
  }
  __syncthreads();

#define TILE128(PC, PN, T)                                                              \
  {                                                                                     \
    bf16x8 afr[2][2], bfr[2];                                                           \
    _Pragma("unroll") for (int mi = 0; mi < 2; ++mi) {                                  \
      afr[mi][0] = *(const bf16x8*)&sA[PC][abase + mi * 2048 + e0];                     \
      afr[mi][1] = *(const bf16x8*)&sA[PC][abase + mi * 2048 + e1];                     \
    }                                                                                   \
    bfr[0] = *(const bf16x8*)&sB[PC][bbase + e0];                                       \
    bfr[1] = *(const bf16x8*)&sB[PC][bbase + e1];                                       \
    if ((T) + 1 < NT) {                                                                 \
      long ks = (long)((T) + 1) * 64;                                                   \
      _Pragma("unroll") for (int i = 0; i < 2; ++i) {                                   \
        gload_lds16(A + a_off[i] + ks, &sA[PN][i * 4096 + ldst]);                       \
        gload_lds16(Bm + b_off[i] + ks, &sB[PN][i * 4096 + ldst]);                      \
      }                                                                                 \
    }                                                                                   \
    __builtin_amdgcn_s_setprio(1);                                                      \
    _Pragma("unroll") for (int mi = 0; mi < 2; ++mi) {                                  \
      acc[mi] = __builtin_amdgcn_mfma_f32_32x32x16_bf16(afr[mi][0], bfr[0], acc[mi], 0, 0, 0); \
      acc[mi] = __builtin_amdgcn_mfma_f32_32x32x16_bf16(afr[mi][1], bfr[1], acc[mi], 0, 0, 0); \
    }                                                                                   \
    __builtin_amdgcn_s_setprio(0);                                                      \
    _Pragma("unroll") for (int mi = 0; mi < 2; ++mi) {                                  \
      afr[mi][0] = *(const bf16x8*)&sA[PC][abase + mi * 2048 + e2];                     \
      afr[mi][1] = *(const bf16x8*)&sA[PC][abase + mi * 2048 + e3];                     \
    }                                                                                   \
    bfr[0] = *(const bf16x8*)&sB[PC][bbase + e2];                                       \
    bfr[1] = *(const bf16x8*)&sB[PC][bbase + e3];                                       \
    __builtin_amdgcn_s_setprio(1);                                                      \
    _Pragma("unroll") for (int mi = 0; mi < 2; ++mi) {                                  \
      acc[mi] = __builtin_amdgcn_mfma_f32_32x32x16_bf16(afr[mi][0], bfr[0], acc[mi], 0, 0, 0); \
      acc[mi] = __builtin_amdgcn_mfma_f32_32x32x16_bf16(afr[mi][1], bfr[1], acc[mi], 0, 0, 0); \
    }                                                                                   \
    __builtin_amdgcn_s_setprio(0);                                                      \
    __syncthreads();                                                                    \
  }

  for (int t = 0; t < NT; t += 2) {
    TILE128(0, 1, t);
    TILE128(1, 0, t + 1);
  }
#undef TILE128

  const int gcol = col0 + wc * 32 + l31;
  const float bz = bias[gcol];
#pragma unroll
  for (int mi = 0; mi < 2; ++mi) {
    const int rbase = row0 + wr * 64 + mi * 32 + 4 * kh;
#pragma unroll
    for (int reg = 0; reg < 16; ++reg) {
      const int grow = rbase + (reg & 3) + 8 * (reg >> 2);
      C[(long)grow * ldc + gcol] = acc[mi][reg] + bz;
    }
  }
}

// ---------------- kv partial: kv[b,h,m,d] = sum_s K'[b,s,h,m]*V[b,s,h,d] ----------------
__global__ __launch_bounds__(256) void kv_partial(
    const bf16_t* __restrict__ QKV, float* __restrict__ kvpart)
{
  int bh = blockIdx.x;
  int split = blockIdx.y;
  int b = bh >> 4, h = bh & 15;
  __shared__ alignas(16) bf16_t Kt[64 * 32];
  __shared__ alignas(16) bf16_t Vt[64 * 32];
  int t = threadIdx.x;
  int wv = t >> 6, lane = t & 63, lhi = lane >> 4, llo = lane & 15;
  int r = t >> 3;
  int c = (t & 7) * 8;
  f32x4 acc[4] = {};
  long rowbase = ((long)b * 4096 + split * 512) * 3072 + h * 64 + c;
  for (int sc = 0; sc < 16; ++sc) {
    long off = rowbase + (long)(sc * 32 + r) * 3072;
    bf16x8 kk = *(const bf16x8*)(QKV + off + 1024);
    bf16x8 vvv = *(const bf16x8*)(QKV + off + 2048);
#pragma unroll
    for (int j = 0; j < 8; ++j) {
      Kt[(c + j) * 32 + r] = kk[j];
      Vt[(c + j) * 32 + r] = vvv[j];
    }
    __syncthreads();
    bf16x8 a = *(const bf16x8*)&Kt[(wv * 16 + llo) * 32 + lhi * 8];
#pragma unroll
    for (int ni = 0; ni < 4; ++ni) {
      bf16x8 bb = *(const bf16x8*)&Vt[(ni * 16 + llo) * 32 + lhi * 8];
      acc[ni] = __builtin_amdgcn_mfma_f32_16x16x32_bf16(a, bb, acc[ni], 0, 0, 0);
    }
    __syncthreads();
  }
#pragma unroll
  for (int ni = 0; ni < 4; ++ni)
#pragma unroll
    for (int j = 0; j < 4; ++j) {
      int m = wv * 16 + lhi * 4 + j;
      int d = ni * 16 + llo;
      kvpart[((long)split * 64 + bh) * 4096 + m * 64 + d] = acc[ni][j];
    }
}

// ---------------- WcombT[b][n][h*64+m] = sum_d kv[b,h,m,d] * Wo[n][h*64+d] -------
// kv materialized in LDS by summing the 8 kvpart splits (kv_reduce fused).
__global__ __launch_bounds__(256) void wcombt_kernel(
    const float* __restrict__ kvpart, const float* __restrict__ Wo,
    bf16_t* __restrict__ WcT)
{
  int nt = blockIdx.x, h = blockIdx.y, b = blockIdx.z;
  __shared__ float kvs[4096];
  int t = threadIdx.x;
  const long base = ((long)b * 16 + h) * 4096;
  for (int i = t * 4; i < 4096; i += 1024) {
    f32x4 s = {0.f, 0.f, 0.f, 0.f};
#pragma unroll
    for (int sp = 0; sp < 8; ++sp)
      s += *(const f32x4*)&kvpart[(long)sp * 262144 + base + i];
    *(f32x4*)&kvs[i] = s;
  }
  __syncthreads();
  int n = nt * 128 + (t >> 1);
  int mh = (t & 1) * 32;
  f32x4 wo[16];
#pragma unroll
  for (int dd = 0; dd < 16; ++dd) wo[dd] = *(const f32x4*)&Wo[(long)n * 1024 + h * 64 + dd * 4];
  for (int m = mh; m < mh + 32; ++m) {
    f32x4 s = {0.f, 0.f, 0.f, 0.f};
#pragma unroll
    for (int dd = 0; dd < 16; ++dd)
      s += (*(const f32x4*)&kvs[m * 64 + dd * 4]) * wo[dd];
    WcT[((long)b * 1024 + n) * 1024 + h * 64 + m] = (bf16_t)(s[0] + s[1] + s[2] + s[3]);
  }
}

// ---------------- launch ----------------
extern "C" void kernel_launch(void* const* d_in, const int* in_sizes, int n_in,
                              void* d_out, int out_size, void* d_ws, size_t ws_size,
                              hipStream_t stream) {
  (void)in_sizes; (void)n_in; (void)out_size; (void)ws_size;
  const float* x  = (const float*)d_in[0];
  const float* Wq = (const float*)d_in[1];
  const float* bq = (const float*)d_in[2];
  const float* Wk = (const float*)d_in[3];
  const float* bk = (const float*)d_in[4];
  const float* Wv = (const float*)d_in[5];
  const float* bv = (const float*)d_in[6];
  const float* Wo = (const float*)d_in[7];
  const float* bo = (const float*)d_in[8];
  const float* P  = (const float*)d_in[9];
  float* out = (float*)d_out;

  char* ws = (char*)d_ws;
  bf16_t* xb     = (bf16_t*)(ws + 0);            // 32 MB
  bf16_t* QKV    = (bf16_t*)(ws + 33554432);     // 96 MB
  bf16_t* Wcat   = (bf16_t*)(ws + 134217728);    // 6 MB
  float*  bcat   = (float*) (ws + 140509184);    // 12 KB
  float*  kvpart = (float*) (ws + 140521472);    // 8 MB
  bf16_t* WcT    = (bf16_t*)(ws + 149958656);    // 8 MB

  // 1. prep: cast kernels (no LDS -> full occupancy) + P-fold (separate, r13 lesson)
  prep_misc<<<8705, 256, 0, stream>>>(x, Wv, bv, xb, Wcat + (size_t)2048 * 1024, bcat);
  prep_wqk<<<256, 256, 0, stream>>>(Wq, bq, Wk, bk, P, Wcat, bcat);

  // 2. fused Q'/K'/V GEMM: [16384,1024] x [3072,1024]^T -> [16384,3072]
  //    grid 64 x 12 = 768 blocks, cpx = 96
  gemm256<1><<<768, 512, 0, stream>>>(
      xb, 1024, Wcat, 1024, bcat, QKV, 3072, 1024, 12, 96, 1 << 30, 0);

  // 3. kv = K'^T @ V per (b,h), 8-way split over s (reduce fused into step 4)
  kv_partial<<<dim3(64, 8), 256, 0, stream>>>(QKV, kvpart);

  // 4. fold kv into Wo: WcombT per batch (sums the 8 splits in-kernel)
  wcombt_kernel<<<dim3(8, 16, 4), 256, 0, stream>>>(kvpart, Wo, WcT);

  // 5. out = Q' @ WcombT[b]^T + bo  (fp32 out) — 128^2 tile, 2 blocks/CU
  //    grid 128 x 8 = 1024 blocks, cpx = 128
  gemm128<<<1024, 512, 0, stream>>>(
      QKV, 3072, WcT, 1024, bo, out, 1024, 1024, 8, 128, 4096, (long)1024 * 1024);
}

// Round 15
// 231.561 us; speedup vs baseline: 1.0682x; 1.0223x over previous
//
#include <hip/hip_runtime.h>
#include <hip/hip_bf16.h>
#include <cstdint>

typedef __bf16 bf16_t;
typedef bf16_t bf16x8 __attribute__((ext_vector_type(8)));
typedef float f32x4 __attribute__((ext_vector_type(4)));
typedef float f32x16 __attribute__((ext_vector_type(16)));

// B=4, S=4096, DIM=1024, H=16, HD=64, M=64
// QKV layout: [16384][3072] bf16, cols 0-1023 = Q', 1024-2047 = K', 2048-3071 = V

__device__ __forceinline__ void gload_lds16(const bf16_t* g, bf16_t* l) {
  __builtin_amdgcn_global_load_lds(
      (const __attribute__((address_space(1))) uint32_t*)g,
      (__attribute__((address_space(3))) uint32_t*)l, 16, 0, 0);
}

// ---------------- merged prep: cast x, cast Wv, copy bv (one launch, NO LDS) ----
__global__ void prep_misc(const float* __restrict__ x, const float* __restrict__ Wv,
                          const float* __restrict__ bv,
                          bf16_t* __restrict__ xb, bf16_t* __restrict__ WvO,
                          float* __restrict__ bcat) {
  int b = blockIdx.x, t = threadIdx.x;
  if (b < 8192) {
    long i = (long)b * 256 + t;
    const f32x4* p = (const f32x4*)(x + i * 8);
    f32x4 a = p[0], c = p[1];
    bf16x8 o;
#pragma unroll
    for (int j = 0; j < 4; ++j) { o[j] = (bf16_t)a[j]; o[j + 4] = (bf16_t)c[j]; }
    *(bf16x8*)(xb + i * 8) = o;
  } else if (b < 8704) {
    long i = (long)(b - 8192) * 256 + t;
    const f32x4* p = (const f32x4*)(Wv + i * 8);
    f32x4 a = p[0], c = p[1];
    bf16x8 o;
#pragma unroll
    for (int j = 0; j < 4; ++j) { o[j] = (bf16_t)a[j]; o[j + 4] = (bf16_t)c[j]; }
    *(bf16x8*)(WvO + i * 8) = o;
  } else {
    *(f32x4*)&bcat[2048 + t * 4] = *(const f32x4*)&bv[t * 4];
  }
}

// ---------------- fold P into Wq/Wk:  WQP[h*64+m][k] = sum_d P[h][m][d]*W[h*64+d][k] ----------------
__global__ __launch_bounds__(256) void prep_wqk(
    const float* __restrict__ Wq, const float* __restrict__ bq,
    const float* __restrict__ Wk, const float* __restrict__ bk,
    const float* __restrict__ P,
    bf16_t* __restrict__ Wcat, float* __restrict__ bcat)
{
  int bid = blockIdx.x;
  int qk = bid >> 7, h = (bid >> 3) & 15, kt = bid & 7;
  const float* W = qk ? Wk : Wq;
  const float* bias = qk ? bk : bq;
  __shared__ float Pl[64 * 64];
  __shared__ float Wlt[128 * 68];
  int t = threadIdx.x;
  int k0 = kt * 128;
  for (int i = t * 4; i < 4096; i += 1024)
    *(f32x4*)&Pl[i] = *(const f32x4*)&P[h * 4096 + i];
  for (int fi = t; fi < 2048; fi += 256) {
    int row = fi >> 5;
    int c4 = fi & 31;
    f32x4 w = *(const f32x4*)&W[(long)(h * 64 + row) * 1024 + k0 + c4 * 4];
#pragma unroll
    for (int j = 0; j < 4; ++j) Wlt[(c4 * 4 + j) * 68 + row] = w[j];
  }
  __syncthreads();
  int kloc = t >> 1;
  int mh = (t & 1) * 32;
  for (int m = mh; m < mh + 32; ++m) {
    f32x4 s = {0.f, 0.f, 0.f, 0.f};
#pragma unroll
    for (int dd = 0; dd < 16; ++dd)
      s += (*(const f32x4*)&Pl[m * 64 + dd * 4]) * (*(const f32x4*)&Wlt[kloc * 68 + dd * 4]);
    float a = s[0] + s[1] + s[2] + s[3];
    Wcat[(long)(qk * 1024 + h * 64 + m) * 1024 + k0 + kloc] = (bf16_t)a;
  }
  if (kt == 0 && t < 64) {
    float a = 0.f;
    for (int d = 0; d < 64; ++d) a += Pl[t * 64 + d] * bias[h * 64 + d];
    bcat[qk * 1024 + h * 64 + t] = a;
  }
}

// ---------------- 256x256 GEMM: r1 loop, 32x32x16 MFMA, XOR-swizzled LDS ---------
// C[M,N] = A[M,K] @ B[N,K]^T + bias.  EPI=1: bf16 out, relu*0.125 for gcol<2048.
// EPI=2: fp32 out.
// Per wave 128x64 = 4(mi,32row) x 2(ni,32col) tiles of f32x16.
// A/B frag: row = l&31, k = (l>>5)*8+elem -> LDS chunk kq = 2*kstep + (l>>5),
// addr = row*64 + (kq ^ (row&7))*8. Note (r9/r10 findings): the residual 9.4M
// bank-conflict count is the 32x32-fragment/row-stride-128B geometry floor
// (~4cyc/b128); removing it requires scattering the staging source (-20%, r10).
template <int EPI>
__global__ __launch_bounds__(512, 2) void gemm256(
    const bf16_t* __restrict__ A, int lda,
    const bf16_t* __restrict__ B0, int ldb,
    const float* __restrict__ bias,
    void* __restrict__ Cv, int ldc,
    int K, int ncols, int cpx,
    int rows_per_batch, long bstride)
{
  __shared__ bf16_t sA[2][16384];
  __shared__ bf16_t sB[2][16384];

  const int lin = blockIdx.x;
  const int wgid = (lin & 7) * cpx + (lin >> 3);
  const int row0 = (wgid / ncols) * 256;
  const int col0 = (wgid % ncols) * 256;

  const int tid = threadIdx.x;
  const int w = tid >> 6, l = tid & 63;
  const int wr = w >> 2, wc = w & 3;          // wave grid 2(M) x 4(N)
  const int l31 = l & 31, kh = l >> 5, x7 = l & 7;

  const bf16_t* Bm = B0 + (long)(row0 / rows_per_batch) * bstride;

  long a_off[4], b_off[4];
#pragma unroll
  for (int i = 0; i < 4; ++i) {
    int c = i * 512 + tid;
    int r = c >> 3;
    int kqs = (c & 7) ^ (r & 7);
    a_off[i] = (long)(row0 + r) * lda + kqs * 8;
    b_off[i] = (long)(col0 + r) * ldb + kqs * 8;
  }
  const int ldst = tid * 8;

  // ds_read bases; chunk offset per kstep s: ((2s + kh) ^ x7) * 8
  const int abase = (wr * 128 + l31) * 64;
  const int bbase = (wc * 64 + l31) * 64;
  const int e0 = ((0 + kh) ^ x7) * 8;   // kstep 0
  const int e1 = ((2 + kh) ^ x7) * 8;   // kstep 1
  const int e2 = ((4 + kh) ^ x7) * 8;   // kstep 2
  const int e3 = ((6 + kh) ^ x7) * 8;   // kstep 3

  f32x16 acc[4][2] = {};
  const int NT = K >> 6;

#pragma unroll
  for (int i = 0; i < 4; ++i) {
    gload_lds16(A + a_off[i], &sA[0][i * 4096 + ldst]);
    gload_lds16(Bm + b_off[i], &sB[0][i * 4096 + ldst]);
  }
  __syncthreads();

#define TILE_BODY(PC, PN, T)                                                            \
  {                                                                                     \
    bf16x8 afr[4][2], bfr[2][2];                                                        \
    _Pragma("unroll") for (int mi = 0; mi < 4; ++mi) {                                  \
      afr[mi][0] = *(const bf16x8*)&sA[PC][abase + mi * 2048 + e0];                     \
      afr[mi][1] = *(const bf16x8*)&sA[PC][abase + mi * 2048 + e1];                     \
    }                                                                                   \
    _Pragma("unroll") for (int ni = 0; ni < 2; ++ni) {                                  \
      bfr[ni][0] = *(const bf16x8*)&sB[PC][bbase + ni * 2048 + e0];                     \
      bfr[ni][1] = *(const bf16x8*)&sB[PC][bbase + ni * 2048 + e1];                     \
    }                                                                                   \
    if ((T) + 1 < NT) {                                                                 \
      long ks = (long)((T) + 1) * 64;                                                   \
      _Pragma("unroll") for (int i = 0; i < 4; ++i) {                                   \
        gload_lds16(A + a_off[i] + ks, &sA[PN][i * 4096 + ldst]);                       \
        gload_lds16(Bm + b_off[i] + ks, &sB[PN][i * 4096 + ldst]);                      \
      }                                                                                 \
    }                                                                                   \
    __builtin_amdgcn_s_setprio(1);                                                      \
    _Pragma("unroll") for (int mi = 0; mi < 4; ++mi)                                    \
      _Pragma("unroll") for (int ni = 0; ni < 2; ++ni) {                                \
        acc[mi][ni] = __builtin_amdgcn_mfma_f32_32x32x16_bf16(afr[mi][0], bfr[ni][0], acc[mi][ni], 0, 0, 0); \
        acc[mi][ni] = __builtin_amdgcn_mfma_f32_32x32x16_bf16(afr[mi][1], bfr[ni][1], acc[mi][ni], 0, 0, 0); \
      }                                                                                 \
    __builtin_amdgcn_s_setprio(0);                                                      \
    _Pragma("unroll") for (int mi = 0; mi < 4; ++mi) {                                  \
      afr[mi][0] = *(const bf16x8*)&sA[PC][abase + mi * 2048 + e2];                     \
      afr[mi][1] = *(const bf16x8*)&sA[PC][abase + mi * 2048 + e3];                     \
    }                                                                                   \
    _Pragma("unroll") for (int ni = 0; ni < 2; ++ni) {                                  \
      bfr[ni][0] = *(const bf16x8*)&sB[PC][bbase + ni * 2048 + e2];                     \
      bfr[ni][1] = *(const bf16x8*)&sB[PC][bbase + ni * 2048 + e3];                     \
    }                                                                                   \
    __builtin_amdgcn_s_setprio(1);                                                      \
    _Pragma("unroll") for (int mi = 0; mi < 4; ++mi)                                    \
      _Pragma("unroll") for (int ni = 0; ni < 2; ++ni) {                                \
        acc[mi][ni] = __builtin_amdgcn_mfma_f32_32x32x16_bf16(afr[mi][0], bfr[ni][0], acc[mi][ni], 0, 0, 0); \
        acc[mi][ni] = __builtin_amdgcn_mfma_f32_32x32x16_bf16(afr[mi][1], bfr[ni][1], acc[mi][ni], 0, 0, 0); \
      }                                                                                 \
    __builtin_amdgcn_s_setprio(0);                                                      \
    __syncthreads();                                                                    \
  }

  for (int t = 0; t < NT; t += 2) {
    TILE_BODY(0, 1, t);
    TILE_BODY(1, 0, t + 1);
  }
#undef TILE_BODY

  // epilogue: 32x32 C/D layout col=lane&31, row=(reg&3)+8*(reg>>2)+4*(lane>>5)
#pragma unroll
  for (int ni = 0; ni < 2; ++ni) {
    const int gcol = col0 + wc * 64 + ni * 32 + l31;
    const float bz = bias[gcol];
    const bool doRelu = (EPI == 1) && (gcol < 2048);
#pragma unroll
    for (int mi = 0; mi < 4; ++mi) {
      const int rbase = row0 + wr * 128 + mi * 32 + 4 * kh;
#pragma unroll
      for (int reg = 0; reg < 16; ++reg) {
        const int grow = rbase + (reg & 3) + 8 * (reg >> 2);
        float v = acc[mi][ni][reg] + bz;
        if constexpr (EPI == 1) { if (doRelu) v = fmaxf(v, 0.f) * 0.125f; }
        if constexpr (EPI == 2)
          ((float*)Cv)[(long)grow * ldc + gcol] = v;
        else
          ((bf16_t*)Cv)[(long)grow * ldc + gcol] = (bf16_t)v;
      }
    }
  }
}

// ---------------- 128x128 GEMM: same loop, 32x32x16, XOR LDS, 2 blocks/CU --------
__global__ __launch_bounds__(512, 4) void gemm128(
    const bf16_t* __restrict__ A, int lda,
    const bf16_t* __restrict__ B0, int ldb,
    const float* __restrict__ bias,
    float* __restrict__ C, int ldc,
    int K, int ncols, int cpx,
    int rows_per_batch, long bstride)
{
  __shared__ bf16_t sA[2][8192];
  __shared__ bf16_t sB[2][8192];

  const int lin = blockIdx.x;
  const int wgid = (lin & 7) * cpx + (lin >> 3);
  const int row0 = (wgid / ncols) * 128;
  const int col0 = (wgid % ncols) * 128;

  const int tid = threadIdx.x;
  const int w = tid >> 6, l = tid & 63;
  const int wr = w >> 2, wc = w & 3;
  const int l31 = l & 31, kh = l >> 5, x7 = l & 7;

  const bf16_t* Bm = B0 + (long)(row0 / rows_per_batch) * bstride;

  long a_off[2], b_off[2];
#pragma unroll
  for (int i = 0; i < 2; ++i) {
    int c = i * 512 + tid;
    int r = c >> 3;
    int kqs = (c & 7) ^ (r & 7);
    a_off[i] = (long)(row0 + r) * lda + kqs * 8;
    b_off[i] = (long)(col0 + r) * ldb + kqs * 8;
  }
  const int ldst = tid * 8;

  const int abase = (wr * 64 + l31) * 64;
  const int bbase = (wc * 32 + l31) * 64;
  const int e0 = ((0 + kh) ^ x7) * 8;
  const int e1 = ((2 + kh) ^ x7) * 8;
  const int e2 = ((4 + kh) ^ x7) * 8;
  const int e3 = ((6 + kh) ^ x7) * 8;

  f32x16 acc[2] = {};
  const int NT = K >> 6;

#pragma unroll
  for (int i = 0; i < 2; ++i) {
    gload_lds16(A + a_off[i], &sA[0][i * 4096 + ldst]);
    gload_lds16(Bm + b_off[i], &sB[0][i * 4096 + ldst]);
  }
  __syncthreads();

#define TILE128(PC, PN, T)                                                              \
  {                                                                                     \
    bf16x8 afr[2][2], bfr[2];                                                           \
    _Pragma("unroll") for (int mi = 0; mi < 2; ++mi) {                                  \
      afr[mi][0] = *(const bf16x8*)&sA[PC][abase + mi * 2048 + e0];                     \
      afr[mi][1] = *(const bf16x8*)&sA[PC][abase + mi * 2048 + e1];                     \
    }                                                                                   \
    bfr[0] = *(const bf16x8*)&sB[PC][bbase + e0];                                       \
    bfr[1] = *(const bf16x8*)&sB[PC][bbase + e1];                                       \
    if ((T) + 1 < NT) {                                                                 \
      long ks = (long)((T) + 1) * 64;                                                   \
      _Pragma("unroll") for (int i = 0; i < 2; ++i) {                                   \
        gload_lds16(A + a_off[i] + ks, &sA[PN][i * 4096 + ldst]);                       \
        gload_lds16(Bm + b_off[i] + ks, &sB[PN][i * 4096 + ldst]);                      \
      }                                                                                 \
    }                                                                                   \
    __builtin_amdgcn_s_setprio(1);                                                      \
    _Pragma("unroll") for (int mi = 0; mi < 2; ++mi) {                                  \
      acc[mi] = __builtin_amdgcn_mfma_f32_32x32x16_bf16(afr[mi][0], bfr[0], acc[mi], 0, 0, 0); \
      acc[mi] = __builtin_amdgcn_mfma_f32_32x32x16_bf16(afr[mi][1], bfr[1], acc[mi], 0, 0, 0); \
    }                                                                                   \
    __builtin_amdgcn_s_setprio(0);                                                      \
    _Pragma("unroll") for (int mi = 0; mi < 2; ++mi) {                                  \
      afr[mi][0] = *(const bf16x8*)&sA[PC][abase + mi * 2048 + e2];                     \
      afr[mi][1] = *(const bf16x8*)&sA[PC][abase + mi * 2048 + e3];                     \
    }                                                                                   \
    bfr[0] = *(const bf16x8*)&sB[PC][bbase + e2];                                       \
    bfr[1] = *(const bf16x8*)&sB[PC][bbase + e3];                                       \
    __builtin_amdgcn_s_setprio(1);                                                      \
    _Pragma("unroll") for (int mi = 0; mi < 2; ++mi) {                                  \
      acc[mi] = __builtin_amdgcn_mfma_f32_32x32x16_bf16(afr[mi][0], bfr[0], acc[mi], 0, 0, 0); \
      acc[mi] = __builtin_amdgcn_mfma_f32_32x32x16_bf16(afr[mi][1], bfr[1], acc[mi], 0, 0, 0); \
    }                                                                                   \
    __builtin_amdgcn_s_setprio(0);                                                      \
    __syncthreads();                                                                    \
  }

  for (int t = 0; t < NT; t += 2) {
    TILE128(0, 1, t);
    TILE128(1, 0, t + 1);
  }
#undef TILE128

  const int gcol = col0 + wc * 32 + l31;
  const float bz = bias[gcol];
#pragma unroll
  for (int mi = 0; mi < 2; ++mi) {
    const int rbase = row0 + wr * 64 + mi * 32 + 4 * kh;
#pragma unroll
    for (int reg = 0; reg < 16; ++reg) {
      const int grow = rbase + (reg & 3) + 8 * (reg >> 2);
      C[(long)grow * ldc + gcol] = acc[mi][reg] + bz;
    }
  }
}

// ---------------- kv partial: kv[b,h,m,d] = sum_s K'[b,s,h,m]*V[b,s,h,d] ----------------
__global__ __launch_bounds__(256) void kv_partial(
    const bf16_t* __restrict__ QKV, float* __restrict__ kvpart)
{
  int bh = blockIdx.x;
  int split = blockIdx.y;
  int b = bh >> 4, h = bh & 15;
  __shared__ alignas(16) bf16_t Kt[64 * 32];
  __shared__ alignas(16) bf16_t Vt[64 * 32];
  int t = threadIdx.x;
  int wv = t >> 6, lane = t & 63, lhi = lane >> 4, llo = lane & 15;
  int r = t >> 3;
  int c = (t & 7) * 8;
  f32x4 acc[4] = {};
  long rowbase = ((long)b * 4096 + split * 512) * 3072 + h * 64 + c;
  for (int sc = 0; sc < 16; ++sc) {
    long off = rowbase + (long)(sc * 32 + r) * 3072;
    bf16x8 kk = *(const bf16x8*)(QKV + off + 1024);
    bf16x8 vvv = *(const bf16x8*)(QKV + off + 2048);
#pragma unroll
    for (int j = 0; j < 8; ++j) {
      Kt[(c + j) * 32 + r] = kk[j];
      Vt[(c + j) * 32 + r] = vvv[j];
    }
    __syncthreads();
    bf16x8 a = *(const bf16x8*)&Kt[(wv * 16 + llo) * 32 + lhi * 8];
#pragma unroll
    for (int ni = 0; ni < 4; ++ni) {
      bf16x8 bb = *(const bf16x8*)&Vt[(ni * 16 + llo) * 32 + lhi * 8];
      acc[ni] = __builtin_amdgcn_mfma_f32_16x16x32_bf16(a, bb, acc[ni], 0, 0, 0);
    }
    __syncthreads();
  }
#pragma unroll
  for (int ni = 0; ni < 4; ++ni)
#pragma unroll
    for (int j = 0; j < 4; ++j) {
      int m = wv * 16 + lhi * 4 + j;
      int d = ni * 16 + llo;
      kvpart[((long)split * 64 + bh) * 4096 + m * 64 + d] = acc[ni][j];
    }
}

__global__ void kv_reduce(const float* __restrict__ part, float* __restrict__ kv) {
  int i = blockIdx.x * 256 + threadIdx.x;
  float s = 0.f;
#pragma unroll
  for (int sp = 0; sp < 8; ++sp) s += part[sp * 262144 + i];
  kv[i] = s;
}

// ---------------- WcombT[b][n][h*64+m] = sum_d kv[b,h,m,d] * Wo[n][h*64+d] ----------------
__global__ __launch_bounds__(256) void wcombt_kernel(
    const float* __restrict__ kv, const float* __restrict__ Wo,
    bf16_t* __restrict__ WcT)
{
  int nt = blockIdx.x, h = blockIdx.y, b = blockIdx.z;
  __shared__ float kvs[4096];
  int t = threadIdx.x;
  for (int i = t * 4; i < 4096; i += 1024)
    *(f32x4*)&kvs[i] = *(const f32x4*)&kv[((long)b * 16 + h) * 4096 + i];
  __syncthreads();
  int n = nt * 128 + (t >> 1);
  int mh = (t & 1) * 32;
  f32x4 wo[16];
#pragma unroll
  for (int dd = 0; dd < 16; ++dd) wo[dd] = *(const f32x4*)&Wo[(long)n * 1024 + h * 64 + dd * 4];
  for (int m = mh; m < mh + 32; ++m) {
    f32x4 s = {0.f, 0.f, 0.f, 0.f};
#pragma unroll
    for (int dd = 0; dd < 16; ++dd)
      s += (*(const f32x4*)&kvs[m * 64 + dd * 4]) * wo[dd];
    WcT[((long)b * 1024 + n) * 1024 + h * 64 + m] = (bf16_t)(s[0] + s[1] + s[2] + s[3]);
  }
}

// ---------------- launch ----------------
extern "C" void kernel_launch(void* const* d_in, const int* in_sizes, int n_in,
                              void* d_out, int out_size, void* d_ws, size_t ws_size,
                              hipStream_t stream) {
  (void)in_sizes; (void)n_in; (void)out_size; (void)ws_size;
  const float* x  = (const float*)d_in[0];
  const float* Wq = (const float*)d_in[1];
  const float* bq = (const float*)d_in[2];
  const float* Wk = (const float*)d_in[3];
  const float* bk = (const float*)d_in[4];
  const float* Wv = (const float*)d_in[5];
  const float* bv = (const float*)d_in[6];
  const float* Wo = (const float*)d_in[7];
  const float* bo = (const float*)d_in[8];
  const float* P  = (const float*)d_in[9];
  float* out = (float*)d_out;

  char* ws = (char*)d_ws;
  bf16_t* xb     = (bf16_t*)(ws + 0);            // 32 MB
  bf16_t* QKV    = (bf16_t*)(ws + 33554432);     // 96 MB
  bf16_t* Wcat   = (bf16_t*)(ws + 134217728);    // 6 MB
  float*  bcat   = (float*) (ws + 140509184);    // 12 KB
  float*  kvpart = (float*) (ws + 140521472);    // 8 MB
  float*  kvbuf  = (float*) (ws + 148910080);    // 1 MB
  bf16_t* WcT    = (bf16_t*)(ws + 149958656);    // 8 MB

  // 1. merged casts + weight prep (separate kernels; r13 lesson: keep cast LDS-free)
  prep_misc<<<8705, 256, 0, stream>>>(x, Wv, bv, xb, Wcat + (size_t)2048 * 1024, bcat);
  prep_wqk<<<256, 256, 0, stream>>>(Wq, bq, Wk, bk, P, Wcat, bcat);

  // 2. fused Q'/K'/V GEMM: [16384,1024] x [3072,1024]^T -> [16384,3072]
  //    grid 64 x 12 = 768 blocks, cpx = 96
  gemm256<1><<<768, 512, 0, stream>>>(
      xb, 1024, Wcat, 1024, bcat, QKV, 3072, 1024, 12, 96, 1 << 30, 0);

  // 3. kv = K'^T @ V per (b,h), 8-way split over s, then clean single-pass reduce
  //    (r14 lesson: fusing the reduce into wcombt re-reads 8x -> keep separate)
  kv_partial<<<dim3(64, 8), 256, 0, stream>>>(QKV, kvpart);
  kv_reduce<<<1024, 256, 0, stream>>>(kvpart, kvbuf);

  // 4. fold kv into Wo: WcombT per batch
  wcombt_kernel<<<dim3(8, 16, 4), 256, 0, stream>>>(kvbuf, Wo, WcT);

  // 5. out = Q' @ WcombT[b]^T + bo  (fp32 out) — 128^2 tile, 2 blocks/CU
  //    grid 128 x 8 = 1024 blocks, cpx = 128
  gemm128<<<1024, 512, 0, stream>>>(
      QKV, 3072, WcT, 1024, bo, out, 1024, 1024, 8, 128, 4096, (long)1024 * 1024);
}